// Round 3
// baseline (489.865 us; speedup 1.0000x reference)
//
#include <hip/hip_runtime.h>

#define KD    512
#define NCLS  100000
#define BC    64
#define NB    ((NCLS + BC - 1) / BC)   // 1563
#define NTILE 1564                     // padded tile count (covers c < 100096)
#define CPAD  100096                   // NTILE*64
#define R1B   64                       // stage-1 reduce blocks
#define R1C   25                       // strips per stage-1 block (64*25 >= 1563)
#define S_SCALE 64.0f
#define COS_M   0.87758256189037276f
#define SIN_M   0.47942553860420301f
#define THRESH (-0.87758256189037276f)
#define MM_C    0.23971276930210151f

typedef __attribute__((ext_vector_type(8))) short short8;
typedef __attribute__((ext_vector_type(4))) float f32x4;

union Pack8 { unsigned short u[8]; uint4 v; };

__device__ __forceinline__ unsigned short f2bf(float x) {
  unsigned int u = __float_as_uint(x);
  u += 0x7fffu + ((u >> 16) & 1u);   // round-to-nearest-even
  return (unsigned short)(u >> 16);
}

// ---- K0: fused row-normalize(e) -> eb bf16, plus per-row target logit ------
__global__ void k0_norm_target(const float* __restrict__ emb, const float* __restrict__ w,
                               const int* __restrict__ label,
                               unsigned short* __restrict__ eb, float* __restrict__ tlA) {
  int r = blockIdx.x;
  int l = threadIdx.x;                 // 64 lanes, 8 elems each
  const float* src = emb + (size_t)r * KD + l * 8;
  float v[8];
  float ss = 0.f;
#pragma unroll
  for (int j = 0; j < 8; ++j) { v[j] = src[j]; ss += v[j] * v[j]; }
#pragma unroll
  for (int m = 1; m < 64; m <<= 1) ss += __shfl_xor(ss, m, 64);
  float rn = rsqrtf(ss);
  Pack8 p;
#pragma unroll
  for (int j = 0; j < 8; ++j) {
    float x = v[j] * rn;
    v[j] = x;                          // normalized fp32 kept in regs
    p.u[j] = f2bf(x);
  }
  *reinterpret_cast<uint4*>(eb + (size_t)r * KD + l * 8) = p.v;

  // target-column dot + its own norm (fp32 path, matches reference gather)
  int lab = label[r];
  float wv[8];
#pragma unroll
  for (int j = 0; j < 8; ++j) wv[j] = w[(size_t)(l * 8 + j) * NCLS + lab];
  float dot = 0.f, sq = 0.f;
#pragma unroll
  for (int j = 0; j < 8; ++j) { dot += v[j] * wv[j]; sq += wv[j] * wv[j]; }
#pragma unroll
  for (int m = 1; m < 64; m <<= 1) {
    dot += __shfl_xor(dot, m, 64);
    sq  += __shfl_xor(sq, m, 64);
  }
  if (l == 0) {
    float tl = dot * rsqrtf(sq);
    tlA[r] = fminf(1.f, fmaxf(-1.f, tl));
  }
}

// ---- K1: t = 0.01*mean(tl); per-row ctm / final ----------------------------
__global__ void k_prep(const float* __restrict__ tlA, float* __restrict__ ctmA,
                       float* __restrict__ finA, float* __restrict__ tval) {
  __shared__ float red[512];
  int i = threadIdx.x;
  float tl = tlA[i];
  red[i] = tl;
  __syncthreads();
  for (int s = 256; s > 0; s >>= 1) {
    if (i < s) red[i] += red[i + s];
    __syncthreads();
  }
  float st = sqrtf(fmaxf(0.f, 1.f - tl * tl));
  float ctm = tl * COS_M - st * SIN_M;
  ctmA[i] = ctm;
  finA[i] = (tl > THRESH) ? ctm : (tl - MM_C);
  if (i == 0) tval[0] = 0.01f * red[0] * (1.f / 512.f);
}

// ---- K_W: stream-pack w (fp32 [512][100000]) into wb bf16 MFMA-fragment
// tiles + per-column sumsq partials. Thread owns ONE column; its 8-k granule
// values arrive via 8 coalesced row-segment loads (1 KB per instruction
// across the wave) -- no LDS, no barriers, no transpose.
// wb tile cb (64 cols x 512 k): byte addr = cb*65536 + o*1024 + ct*256 + cl*16
//   where o = k>>3 (k-octet), ct = (c>>4)&3, cl = c&15.
// Grid: 391 col-chunks (256 cols) x 4 k-quarters = 1564 blocks.
__global__ __launch_bounds__(256)
void k_w(const float* __restrict__ w, unsigned short* __restrict__ wb,
         float* __restrict__ sqpart) {
  const int tid = threadIdx.x;
  const int ch  = blockIdx.x >> 2;
  const int kh  = blockIdx.x & 3;
  const int c   = ch * 256 + tid;          // 0..100095
  const int cc  = (c < NCLS) ? c : (NCLS - 1);
  const bool valid = (c < NCLS);
  const int cb = c >> 6;
  const int ct = (c >> 4) & 3;
  const int cl = c & 15;
  unsigned short* gdst = wb + (size_t)cb * 32768 + ct * 128 + cl * 8;  // ushort units
  const float* srcc = w + cc;
  float sq = 0.f;
#pragma unroll 2
  for (int o16 = 0; o16 < 16; ++o16) {
    const int o = kh * 16 + o16;           // k-octet 0..63
    float v[8];
#pragma unroll
    for (int j = 0; j < 8; ++j)
      v[j] = srcc[(size_t)(o * 8 + j) * NCLS];
    Pack8 p;
#pragma unroll
    for (int j = 0; j < 8; ++j) {
      float x = valid ? v[j] : 0.f;
      sq += x * x;
      p.u[j] = f2bf(x);
    }
    *reinterpret_cast<uint4*>(gdst + (size_t)o * 512) = p.v;
  }
  sqpart[(size_t)kh * CPAD + c] = sq;
}

// ---- K2 (new): bf16 MFMA GEMM, B fragments loaded DIRECTLY from wb ---------
// No B staging, no pack, no mid-kernel barrier drains. wb is L2/L3-resident.
// A fragments from L2-resident eb. invn reduced in-block from sqpart.
__global__ __launch_bounds__(256, 2)
void k_gemm(const unsigned short* __restrict__ wb, const float* __restrict__ sqpart,
            const unsigned short* __restrict__ eb,
            const int* __restrict__ label, const float* __restrict__ ctmA,
            const float* __restrict__ finA, const float* __restrict__ tval,
            float2* __restrict__ part) {
  __shared__ float invnS[BC];
  __shared__ float sE[512];
  __shared__ float sL[512];
  const int tid = threadIdx.x;
  const int wv = tid >> 6;             // wave 0..3
  const int l  = tid & 63;
  const int c0 = blockIdx.x * BC;

  if (tid < BC) {
    const int c = c0 + tid;            // < 100032 <= CPAD, always in range
    float s = sqpart[0 * (size_t)CPAD + c] + sqpart[1 * (size_t)CPAD + c]
            + sqpart[2 * (size_t)CPAD + c] + sqpart[3 * (size_t)CPAD + c];
    invnS[tid] = (s > 0.f) ? rsqrtf(s) : 0.f;
  }
  __syncthreads();

  const int q  = l >> 4;
  const int cl = l & 15;
  const int rbase = wv * 128;
  // per-lane base into this block's wb tile (ushort units):
  // byte = blockIdx.x*65536 + q*1024 + cl*16 (+ s*4096 + ct*256 in-loop)
  const unsigned short* bt = wb + (size_t)blockIdx.x * 32768 + q * 512 + cl * 8;
  f32x4 acc[8][4] = {};

#pragma unroll 1
  for (int s = 0; s < 16; ++s) {
    const int k0 = s * 32 + q * 8;
    short8 a[8], b[4];
#pragma unroll
    for (int ct = 0; ct < 4; ++ct)
      b[ct] = *reinterpret_cast<const short8*>(bt + s * 2048 + ct * 128);
#pragma unroll
    for (int rt = 0; rt < 8; ++rt) {
      int row = rbase + rt * 16 + cl;
      a[rt] = *reinterpret_cast<const short8*>(eb + (size_t)row * KD + k0);
    }
#pragma unroll
    for (int rt = 0; rt < 8; ++rt)
#pragma unroll
      for (int ct = 0; ct < 4; ++ct)
        acc[rt][ct] = __builtin_amdgcn_mfma_f32_16x16x32_bf16(a[rt], b[ct], acc[rt][ct], 0, 0, 0);
  }

  // ---- epilogue: colnorm + transform + per-row sums into LDS ----
  // FULLY unrolled: every acc index compile-time constant (rule #20).
  const float t = tval[0];
#pragma unroll
  for (int rt = 0; rt < 8; ++rt) {
#pragma unroll
    for (int rg = 0; rg < 4; ++rg) {
      const int row = rbase + rt * 16 + q * 4 + rg;
      const float ctm = ctmA[row];
      const float fin = finA[row];
      const int   lab = label[row];
      float se = 0.f, sl = 0.f;
#pragma unroll
      for (int ct = 0; ct < 4; ++ct) {
        const int cg = c0 + ct * 16 + cl;
        if (cg < NCLS) {
          float cosv = acc[rt][ct][rg] * invnS[ct * 16 + cl];
          cosv = fminf(1.f, fmaxf(-1.f, cosv));
          float logit = (cosv > ctm) ? cosv * (t + cosv) : cosv;
          if (cg == lab) logit = fin;
          float x = S_SCALE * logit;
          se += __expf(x);
          sl += x;
        }
      }
#pragma unroll
      for (int m = 1; m < 16; m <<= 1) {
        se += __shfl_xor(se, m, 64);
        sl += __shfl_xor(sl, m, 64);
      }
      if (cl == 0) { sE[row] = se; sL[row] = sl; }
    }
  }
  __syncthreads();

  {
    float2* dst = part + (size_t)blockIdx.x * 512;
    dst[tid]       = make_float2(sE[tid],       sL[tid]);
    dst[tid + 256] = make_float2(sE[tid + 256], sL[tid + 256]);
  }
}

// ---- Legacy one-pass GEMM (fallback if workspace too small) ---------------
__global__ __launch_bounds__(256, 2)
void k_gemm_legacy(const float* __restrict__ w, const unsigned short* __restrict__ eb,
            const int* __restrict__ label, const float* __restrict__ ctmA,
            const float* __restrict__ finA, const float* __restrict__ tval,
            float2* __restrict__ part) {
  __shared__ __align__(16) unsigned short Bs[BC * KD];   // 64 KB
  __shared__ float ssW[4][BC];
  __shared__ float invnS[BC];
  __shared__ float sE[512];
  __shared__ float sL[512];
  const int tid = threadIdx.x;
  const int wv = tid >> 6;
  const int l  = tid & 63;
  const int c0 = blockIdx.x * BC;
  {
    const int c = l;
    const int cgc = (c0 + c < NCLS) ? (c0 + c) : (NCLS - 1);
    const float* wp = w + cgc;
    float ss = 0.f;
#pragma unroll 1
    for (int ph = 0; ph < 2; ++ph) {
      float vb[8][8];
#pragma unroll
      for (int b = 0; b < 8; ++b) {
        const int kb = wv * 8 + (ph * 8 + b) * 32;
#pragma unroll
        for (int j = 0; j < 8; ++j)
          vb[b][j] = __builtin_nontemporal_load(&wp[(size_t)(kb + j) * NCLS]);
      }
      __builtin_amdgcn_sched_barrier(0);
#pragma unroll
      for (int b = 0; b < 8; ++b) {
        const int kb = wv * 8 + (ph * 8 + b) * 32;
        Pack8 p;
#pragma unroll
        for (int j = 0; j < 8; ++j) {
          float x = vb[b][j];
          ss += x * x;
          p.u[j] = f2bf(x);
        }
        const int G = c * 64 + ((kb >> 3) ^ (c & 7));
        *reinterpret_cast<uint4*>(&Bs[G * 8]) = p.v;
      }
    }
    ssW[wv][c] = ss;
  }
  __syncthreads();
  if (tid < BC) {
    float s = ssW[0][tid] + ssW[1][tid] + ssW[2][tid] + ssW[3][tid];
    invnS[tid] = (s > 0.f) ? rsqrtf(s) : 0.f;
  }
  __syncthreads();
  const int q  = l >> 4;
  const int cl = l & 15;
  const int rbase = wv * 128;
  f32x4 acc[8][4] = {};
#pragma unroll 1
  for (int s = 0; s < 16; ++s) {
    const int k0 = s * 32 + q * 8;
    short8 a[8], b[4];
#pragma unroll
    for (int ct = 0; ct < 4; ++ct) {
      int c = ct * 16 + cl;
      int G = c * 64 + ((k0 >> 3) ^ (c & 7));
      b[ct] = *reinterpret_cast<const short8*>(&Bs[G * 8]);
    }
#pragma unroll
    for (int rt = 0; rt < 8; ++rt) {
      int row = rbase + rt * 16 + cl;
      a[rt] = *reinterpret_cast<const short8*>(eb + (size_t)row * KD + k0);
    }
#pragma unroll
    for (int rt = 0; rt < 8; ++rt)
#pragma unroll
      for (int ct = 0; ct < 4; ++ct)
        acc[rt][ct] = __builtin_amdgcn_mfma_f32_16x16x32_bf16(a[rt], b[ct], acc[rt][ct], 0, 0, 0);
  }
  const float t = tval[0];
#pragma unroll
  for (int rt = 0; rt < 8; ++rt) {
#pragma unroll
    for (int rg = 0; rg < 4; ++rg) {
      const int row = rbase + rt * 16 + q * 4 + rg;
      const float ctm = ctmA[row];
      const float fin = finA[row];
      const int   lab = label[row];
      float se = 0.f, sl = 0.f;
#pragma unroll
      for (int ct = 0; ct < 4; ++ct) {
        const int cg = c0 + ct * 16 + cl;
        if (cg < NCLS) {
          float cosv = acc[rt][ct][rg] * invnS[ct * 16 + cl];
          cosv = fminf(1.f, fmaxf(-1.f, cosv));
          float logit = (cosv > ctm) ? cosv * (t + cosv) : cosv;
          if (cg == lab) logit = fin;
          float x = S_SCALE * logit;
          se += __expf(x);
          sl += x;
        }
      }
#pragma unroll
      for (int m = 1; m < 16; m <<= 1) {
        se += __shfl_xor(se, m, 64);
        sl += __shfl_xor(sl, m, 64);
      }
      if (cl == 0) { sE[row] = se; sL[row] = sl; }
    }
  }
  __syncthreads();
  {
    float2* dst = part + (size_t)blockIdx.x * 512;
    dst[tid]       = make_float2(sE[tid],       sL[tid]);
    dst[tid + 256] = make_float2(sE[tid + 256], sL[tid + 256]);
  }
}

// ---- K3a: stage-1 reduce over strips (coalesced) ---------------------------
__global__ void k_reduce1(const float2* __restrict__ part, float2* __restrict__ part2) {
  const int j = blockIdx.x;            // 0..63
  const int r = threadIdx.x;           // 0..511
  const int i0 = j * R1C;
  const int i1 = (i0 + R1C < NB) ? (i0 + R1C) : NB;
  float se = 0.f, sl = 0.f;
  for (int i = i0; i < i1; ++i) {
    float2 p = part[(size_t)i * 512 + r];
    se += p.x; sl += p.y;
  }
  part2[(size_t)j * 512 + r] = make_float2(se, sl);
}

// ---- K3b: stage-2 reduce + final loss (single block) -----------------------
__global__ void k_loss(const float2* __restrict__ part2, const float* __restrict__ finA,
                       float* __restrict__ out) {
  __shared__ float red[512];
  const int r = threadIdx.x;           // 0..511
  float se = 0.f, sl = 0.f;
#pragma unroll 4
  for (int j = 0; j < R1B; ++j) {
    float2 p = part2[(size_t)j * 512 + r];
    se += p.x; sl += p.y;
  }
  float lse = logf(se);                // no max-shift: se < 1e34
  float nll = lse - S_SCALE * finA[r];
  float sm  = lse - sl * (1.f / (float)NCLS);
  red[r] = 0.9f * nll + 0.1f * sm;
  __syncthreads();
  for (int s = 256; s > 0; s >>= 1) {
    if (r < s) red[r] += red[r + s];
    __syncthreads();
  }
  if (r == 0) out[0] = red[0] * (1.f / 512.f);
}

extern "C" void kernel_launch(void* const* d_in, const int* in_sizes, int n_in,
                              void* d_out, int out_size, void* d_ws, size_t ws_size,
                              hipStream_t stream) {
  (void)in_sizes; (void)n_in; (void)out_size;
  const float* emb = (const float*)d_in[0];
  const float* w   = (const float*)d_in[1];
  const int*   lab = (const int*)d_in[2];
  float* out = (float*)d_out;

  char* ws = (char*)d_ws;
  unsigned short* eb = (unsigned short*)ws;                       // 512 KB
  float* tlA   = (float*)(ws + 524288);
  float* ctmA  = tlA  + 512;
  float* finA  = ctmA + 512;
  float* tval  = finA + 512;
  float2* part  = (float2*)(ws + 524288 + 8192);                  // NB*512*8 = 6.4 MB
  float2* part2 = part + (size_t)NB * 512;                        // 64*512*8 = 256 KB
  // new-path buffers
  const size_t wb_off = 7196672;                                  // end of part2, aligned
  unsigned short* wb = (unsigned short*)(ws + wb_off);            // NTILE*64KB = 102.5 MB
  float* sqpart = (float*)(ws + wb_off + (size_t)NTILE * 65536);  // 4*CPAD*4 = 1.6 MB
  const size_t need = wb_off + (size_t)NTILE * 65536 + (size_t)4 * CPAD * 4;

  if (ws_size >= need) {
    hipLaunchKernelGGL(k_w,  dim3(1564), dim3(256), 0, stream, w, wb, sqpart);
    hipLaunchKernelGGL(k0_norm_target, dim3(512), dim3(64), 0, stream, emb, w, lab, eb, tlA);
    hipLaunchKernelGGL(k_prep, dim3(1), dim3(512), 0, stream, tlA, ctmA, finA, tval);
    hipLaunchKernelGGL(k_gemm, dim3(NB), dim3(256), 0, stream,
                       wb, sqpart, eb, lab, ctmA, finA, tval, part);
  } else {
    hipLaunchKernelGGL(k0_norm_target, dim3(512), dim3(64), 0, stream, emb, w, lab, eb, tlA);
    hipLaunchKernelGGL(k_prep, dim3(1), dim3(512), 0, stream, tlA, ctmA, finA, tval);
    hipLaunchKernelGGL(k_gemm_legacy, dim3(NB), dim3(256), 0, stream,
                       w, eb, lab, ctmA, finA, tval, part);
  }
  hipLaunchKernelGGL(k_reduce1, dim3(R1B), dim3(512), 0, stream, part, part2);
  hipLaunchKernelGGL(k_loss,    dim3(1),   dim3(512), 0, stream, part2, finA, out);
}

// Round 4
// 469.162 us; speedup vs baseline: 1.0441x; 1.0441x over previous
//
#include <hip/hip_runtime.h>

#define KD    512
#define NCLS  100000
#define BC    64
#define NB    ((NCLS + BC - 1) / BC)   // 1563
#define NTILE 1564                     // padded tile count (covers c < 100096)
#define CPAD  100096                   // NTILE*64
#define R1B   64                       // stage-1 reduce blocks
#define R1C   25                       // strips per stage-1 block (64*25 >= 1563)
#define S_SCALE 64.0f
#define COS_M   0.87758256189037276f
#define SIN_M   0.47942553860420301f
#define THRESH (-0.87758256189037276f)
#define MM_C    0.23971276930210151f

typedef __attribute__((ext_vector_type(8))) short short8;
typedef __attribute__((ext_vector_type(4))) float f32x4;

union Pack8 { unsigned short u[8]; uint4 v; };

__device__ __forceinline__ unsigned short f2bf(float x) {
  unsigned int u = __float_as_uint(x);
  u += 0x7fffu + ((u >> 16) & 1u);   // round-to-nearest-even
  return (unsigned short)(u >> 16);
}

// ---- K0 (new): row-normalize(e) -> eb bf16 + rn per row --------------------
__global__ void k0_norm(const float* __restrict__ emb,
                        unsigned short* __restrict__ eb, float* __restrict__ rnA) {
  int r = blockIdx.x;
  int l = threadIdx.x;                 // 64 lanes, 8 elems each
  const float* src = emb + (size_t)r * KD + l * 8;
  float v[8];
  float ss = 0.f;
#pragma unroll
  for (int j = 0; j < 8; ++j) { v[j] = src[j]; ss += v[j] * v[j]; }
#pragma unroll
  for (int m = 1; m < 64; m <<= 1) ss += __shfl_xor(ss, m, 64);
  float rn = rsqrtf(ss);
  Pack8 p;
#pragma unroll
  for (int j = 0; j < 8; ++j) p.u[j] = f2bf(v[j] * rn);
  *reinterpret_cast<uint4*>(eb + (size_t)r * KD + l * 8) = p.v;
  if (l == 0) rnA[r] = rn;
}

// ---- K_TGT: k-blocked target-column gather (DRAM row-burst locality) -------
// Block j owns k in [j*8, j*8+8). All 512 threads hit w-row k together:
// 512 scattered 4B touches inside ONE 400 KB row region per step, 64 blocks
// across the chip. Replaces the old per-sample 400KB-strided column walk
// (262144 isolated random DRAM touches, 1 wave/block -> latency-bound).
__global__ __launch_bounds__(512)
void k_tgt(const float* __restrict__ emb, const float* __restrict__ w,
           const int* __restrict__ label, float2* __restrict__ tpart) {
  const int j = blockIdx.x;            // 0..63
  const int r = threadIdx.x;           // 0..511
  const int lab = label[r];
  const float* wc = w + lab;
  const float* er = emb + (size_t)r * KD + j * 8;
  float dot = 0.f, sq = 0.f;
#pragma unroll
  for (int kk = 0; kk < 8; ++kk) {
    float wv = wc[(size_t)(j * 8 + kk) * NCLS];
    float ev = er[kk];
    dot += ev * wv;
    sq  += wv * wv;
  }
  tpart[(size_t)j * 512 + r] = make_float2(dot, sq);
}

// ---- K_PREP2: reduce tpart -> tl; ctm/fin per row; t scalar ---------------
__global__ void k_prep2(const float2* __restrict__ tpart, const float* __restrict__ rnA,
                        float* __restrict__ ctmA, float* __restrict__ finA,
                        float* __restrict__ tval) {
  __shared__ float red[512];
  const int r = threadIdx.x;
  float dot = 0.f, sq = 0.f;
#pragma unroll 8
  for (int j = 0; j < 64; ++j) {
    float2 p = tpart[(size_t)j * 512 + r];
    dot += p.x; sq += p.y;
  }
  float tl = dot * rnA[r] * rsqrtf(sq);
  tl = fminf(1.f, fmaxf(-1.f, tl));
  red[r] = tl;
  __syncthreads();
  for (int s = 256; s > 0; s >>= 1) {
    if (r < s) red[r] += red[r + s];
    __syncthreads();
  }
  float st = sqrtf(fmaxf(0.f, 1.f - tl * tl));
  float ctm = tl * COS_M - st * SIN_M;
  ctmA[r] = ctm;
  finA[r] = (tl > THRESH) ? ctm : (tl - MM_C);
  if (r == 0) tval[0] = 0.01f * red[0] * (1.f / 512.f);
}

// ---- K_W: stream-pack w (fp32 [512][100000]) into wb bf16 MFMA-fragment
// tiles + per-column sumsq partials. 1024-thread blocks: each (k-row, j) step
// reads 4 KB contiguous per block (better DRAM sequentiality than 1 KB).
// wb tile cb (64 cols x 512 k): ushort addr = cb*32768 + o*512 + ct*128 + cl*8
//   where o = k>>3 (k-octet), ct = (c>>4)&3, cl = c&15.
// Grid: 98 col-chunks (1024 cols) x 4 k-quarters = 392 blocks.
__global__ __launch_bounds__(1024)
void k_w(const float* __restrict__ w, unsigned short* __restrict__ wb,
         float* __restrict__ sqpart) {
  const int tid = threadIdx.x;
  const int ch  = blockIdx.x >> 2;
  const int kh  = blockIdx.x & 3;
  const int c   = ch * 1024 + tid;         // 0..100351
  const int cc  = (c < NCLS) ? c : (NCLS - 1);
  const bool valid = (c < NCLS);
  const bool wvalid = (c < CPAD);          // tiles exist only for c < 100096
  const int cb = c >> 6;
  const int ct = (c >> 4) & 3;
  const int cl = c & 15;
  unsigned short* gdst = wb + (size_t)cb * 32768 + ct * 128 + cl * 8;  // ushort units
  const float* srcc = w + cc;
  float sq = 0.f;
#pragma unroll 2
  for (int o16 = 0; o16 < 16; ++o16) {
    const int o = kh * 16 + o16;           // k-octet 0..63
    float v[8];
#pragma unroll
    for (int j = 0; j < 8; ++j)
      v[j] = __builtin_nontemporal_load(&srcc[(size_t)(o * 8 + j) * NCLS]);
    Pack8 p;
#pragma unroll
    for (int j = 0; j < 8; ++j) {
      float x = valid ? v[j] : 0.f;
      sq += x * x;
      p.u[j] = f2bf(x);
    }
    if (wvalid) *reinterpret_cast<uint4*>(gdst + (size_t)o * 512) = p.v;
  }
  if (wvalid) sqpart[(size_t)kh * CPAD + c] = sq;
}

// ---- K2: bf16 MFMA GEMM, 8 waves x (64 rows x 64 cols), direct wb loads ----
// acc = 4x4 f32x4 = 64 regs/wave -> launch_bounds(512,4) holds VGPR <= 128,
// 16 waves/CU (was 8). Loop latency hidden by TLP, not pipelining.
__global__ __launch_bounds__(512, 4)
void k_gemm(const unsigned short* __restrict__ wb, const float* __restrict__ sqpart,
            const unsigned short* __restrict__ eb,
            const int* __restrict__ label, const float* __restrict__ ctmA,
            const float* __restrict__ finA, const float* __restrict__ tval,
            float2* __restrict__ part) {
  __shared__ float invnS[BC];
  __shared__ float sE[512];
  __shared__ float sL[512];
  const int tid = threadIdx.x;
  const int wv = tid >> 6;             // wave 0..7
  const int l  = tid & 63;
  const int c0 = blockIdx.x * BC;

  if (tid < BC) {
    const int c = c0 + tid;            // < 100096 <= CPAD
    float s = sqpart[0 * (size_t)CPAD + c] + sqpart[1 * (size_t)CPAD + c]
            + sqpart[2 * (size_t)CPAD + c] + sqpart[3 * (size_t)CPAD + c];
    invnS[tid] = (s > 0.f) ? rsqrtf(s) : 0.f;
  }
  __syncthreads();

  const int q  = l >> 4;
  const int cl = l & 15;
  const int rbase = wv * 64;
  const unsigned short* bt = wb + (size_t)blockIdx.x * 32768 + q * 512 + cl * 8;
  f32x4 acc[4][4] = {};

#pragma unroll 1
  for (int s = 0; s < 16; ++s) {
    const int k0 = s * 32 + q * 8;
    short8 a[4], b[4];
#pragma unroll
    for (int ct = 0; ct < 4; ++ct)
      b[ct] = *reinterpret_cast<const short8*>(bt + s * 2048 + ct * 128);
#pragma unroll
    for (int rt = 0; rt < 4; ++rt) {
      int row = rbase + rt * 16 + cl;
      a[rt] = *reinterpret_cast<const short8*>(eb + (size_t)row * KD + k0);
    }
#pragma unroll
    for (int rt = 0; rt < 4; ++rt)
#pragma unroll
      for (int ct = 0; ct < 4; ++ct)
        acc[rt][ct] = __builtin_amdgcn_mfma_f32_16x16x32_bf16(a[rt], b[ct], acc[rt][ct], 0, 0, 0);
  }

  // ---- epilogue: colnorm + transform + per-row sums (all indices static) ---
  const float t = tval[0];
#pragma unroll
  for (int rt = 0; rt < 4; ++rt) {
#pragma unroll
    for (int rg = 0; rg < 4; ++rg) {
      const int row = rbase + rt * 16 + q * 4 + rg;
      const float ctm = ctmA[row];
      const float fin = finA[row];
      const int   lab = label[row];
      float se = 0.f, sl = 0.f;
#pragma unroll
      for (int ct = 0; ct < 4; ++ct) {
        const int cg = c0 + ct * 16 + cl;
        if (cg < NCLS) {
          float cosv = acc[rt][ct][rg] * invnS[ct * 16 + cl];
          cosv = fminf(1.f, fmaxf(-1.f, cosv));
          float logit = (cosv > ctm) ? cosv * (t + cosv) : cosv;
          if (cg == lab) logit = fin;
          float x = S_SCALE * logit;
          se += __expf(x);
          sl += x;
        }
      }
#pragma unroll
      for (int m = 1; m < 16; m <<= 1) {
        se += __shfl_xor(se, m, 64);
        sl += __shfl_xor(sl, m, 64);
      }
      if (cl == 0) { sE[row] = se; sL[row] = sl; }
    }
  }
  __syncthreads();

  part[(size_t)blockIdx.x * 512 + tid] = make_float2(sE[tid], sL[tid]);
}

// ================= legacy fallback path (R2 kernel set) =====================
__global__ void k0_norm_target_legacy(const float* __restrict__ emb, const float* __restrict__ w,
                               const int* __restrict__ label,
                               unsigned short* __restrict__ eb, float* __restrict__ tlA) {
  int r = blockIdx.x;
  int l = threadIdx.x;
  const float* src = emb + (size_t)r * KD + l * 8;
  float v[8];
  float ss = 0.f;
#pragma unroll
  for (int j = 0; j < 8; ++j) { v[j] = src[j]; ss += v[j] * v[j]; }
#pragma unroll
  for (int m = 1; m < 64; m <<= 1) ss += __shfl_xor(ss, m, 64);
  float rn = rsqrtf(ss);
  Pack8 p;
#pragma unroll
  for (int j = 0; j < 8; ++j) {
    float x = v[j] * rn;
    v[j] = x;
    p.u[j] = f2bf(x);
  }
  *reinterpret_cast<uint4*>(eb + (size_t)r * KD + l * 8) = p.v;
  int lab = label[r];
  float wv[8];
#pragma unroll
  for (int j = 0; j < 8; ++j) wv[j] = w[(size_t)(l * 8 + j) * NCLS + lab];
  float dot = 0.f, sq = 0.f;
#pragma unroll
  for (int j = 0; j < 8; ++j) { dot += v[j] * wv[j]; sq += wv[j] * wv[j]; }
#pragma unroll
  for (int m = 1; m < 64; m <<= 1) {
    dot += __shfl_xor(dot, m, 64);
    sq  += __shfl_xor(sq, m, 64);
  }
  if (l == 0) {
    float tl = dot * rsqrtf(sq);
    tlA[r] = fminf(1.f, fmaxf(-1.f, tl));
  }
}

__global__ void k_prep(const float* __restrict__ tlA, float* __restrict__ ctmA,
                       float* __restrict__ finA, float* __restrict__ tval) {
  __shared__ float red[512];
  int i = threadIdx.x;
  float tl = tlA[i];
  red[i] = tl;
  __syncthreads();
  for (int s = 256; s > 0; s >>= 1) {
    if (i < s) red[i] += red[i + s];
    __syncthreads();
  }
  float st = sqrtf(fmaxf(0.f, 1.f - tl * tl));
  float ctm = tl * COS_M - st * SIN_M;
  ctmA[i] = ctm;
  finA[i] = (tl > THRESH) ? ctm : (tl - MM_C);
  if (i == 0) tval[0] = 0.01f * red[0] * (1.f / 512.f);
}

__global__ __launch_bounds__(256, 2)
void k_gemm_legacy(const float* __restrict__ w, const unsigned short* __restrict__ eb,
            const int* __restrict__ label, const float* __restrict__ ctmA,
            const float* __restrict__ finA, const float* __restrict__ tval,
            float2* __restrict__ part) {
  __shared__ __align__(16) unsigned short Bs[BC * KD];
  __shared__ float ssW[4][BC];
  __shared__ float invnS[BC];
  __shared__ float sE[512];
  __shared__ float sL[512];
  const int tid = threadIdx.x;
  const int wv = tid >> 6;
  const int l  = tid & 63;
  const int c0 = blockIdx.x * BC;
  {
    const int c = l;
    const int cgc = (c0 + c < NCLS) ? (c0 + c) : (NCLS - 1);
    const float* wp = w + cgc;
    float ss = 0.f;
#pragma unroll 1
    for (int ph = 0; ph < 2; ++ph) {
      float vb[8][8];
#pragma unroll
      for (int b = 0; b < 8; ++b) {
        const int kb = wv * 8 + (ph * 8 + b) * 32;
#pragma unroll
        for (int j = 0; j < 8; ++j)
          vb[b][j] = __builtin_nontemporal_load(&wp[(size_t)(kb + j) * NCLS]);
      }
      __builtin_amdgcn_sched_barrier(0);
#pragma unroll
      for (int b = 0; b < 8; ++b) {
        const int kb = wv * 8 + (ph * 8 + b) * 32;
        Pack8 p;
#pragma unroll
        for (int j = 0; j < 8; ++j) {
          float x = vb[b][j];
          ss += x * x;
          p.u[j] = f2bf(x);
        }
        const int G = c * 64 + ((kb >> 3) ^ (c & 7));
        *reinterpret_cast<uint4*>(&Bs[G * 8]) = p.v;
      }
    }
    ssW[wv][c] = ss;
  }
  __syncthreads();
  if (tid < BC) {
    float s = ssW[0][tid] + ssW[1][tid] + ssW[2][tid] + ssW[3][tid];
    invnS[tid] = (s > 0.f) ? rsqrtf(s) : 0.f;
  }
  __syncthreads();
  const int q  = l >> 4;
  const int cl = l & 15;
  const int rbase = wv * 128;
  f32x4 acc[8][4] = {};
#pragma unroll 1
  for (int s = 0; s < 16; ++s) {
    const int k0 = s * 32 + q * 8;
    short8 a[8], b[4];
#pragma unroll
    for (int ct = 0; ct < 4; ++ct) {
      int c = ct * 16 + cl;
      int G = c * 64 + ((k0 >> 3) ^ (c & 7));
      b[ct] = *reinterpret_cast<const short8*>(&Bs[G * 8]);
    }
#pragma unroll
    for (int rt = 0; rt < 8; ++rt) {
      int row = rbase + rt * 16 + cl;
      a[rt] = *reinterpret_cast<const short8*>(eb + (size_t)row * KD + k0);
    }
#pragma unroll
    for (int rt = 0; rt < 8; ++rt)
#pragma unroll
      for (int ct = 0; ct < 4; ++ct)
        acc[rt][ct] = __builtin_amdgcn_mfma_f32_16x16x32_bf16(a[rt], b[ct], acc[rt][ct], 0, 0, 0);
  }
  const float t = tval[0];
#pragma unroll
  for (int rt = 0; rt < 8; ++rt) {
#pragma unroll
    for (int rg = 0; rg < 4; ++rg) {
      const int row = rbase + rt * 16 + q * 4 + rg;
      const float ctm = ctmA[row];
      const float fin = finA[row];
      const int   lab = label[row];
      float se = 0.f, sl = 0.f;
#pragma unroll
      for (int ct = 0; ct < 4; ++ct) {
        const int cg = c0 + ct * 16 + cl;
        if (cg < NCLS) {
          float cosv = acc[rt][ct][rg] * invnS[ct * 16 + cl];
          cosv = fminf(1.f, fmaxf(-1.f, cosv));
          float logit = (cosv > ctm) ? cosv * (t + cosv) : cosv;
          if (cg == lab) logit = fin;
          float x = S_SCALE * logit;
          se += __expf(x);
          sl += x;
        }
      }
#pragma unroll
      for (int m = 1; m < 16; m <<= 1) {
        se += __shfl_xor(se, m, 64);
        sl += __shfl_xor(sl, m, 64);
      }
      if (cl == 0) { sE[row] = se; sL[row] = sl; }
    }
  }
  __syncthreads();
  {
    float2* dst = part + (size_t)blockIdx.x * 512;
    dst[tid]       = make_float2(sE[tid],       sL[tid]);
    dst[tid + 256] = make_float2(sE[tid + 256], sL[tid + 256]);
  }
}

// ---- K3a: stage-1 reduce over strips (coalesced) ---------------------------
__global__ void k_reduce1(const float2* __restrict__ part, float2* __restrict__ part2) {
  const int j = blockIdx.x;            // 0..63
  const int r = threadIdx.x;           // 0..511
  const int i0 = j * R1C;
  const int i1 = (i0 + R1C < NB) ? (i0 + R1C) : NB;
  float se = 0.f, sl = 0.f;
  for (int i = i0; i < i1; ++i) {
    float2 p = part[(size_t)i * 512 + r];
    se += p.x; sl += p.y;
  }
  part2[(size_t)j * 512 + r] = make_float2(se, sl);
}

// ---- K3b: stage-2 reduce + final loss (single block) -----------------------
__global__ void k_loss(const float2* __restrict__ part2, const float* __restrict__ finA,
                       float* __restrict__ out) {
  __shared__ float red[512];
  const int r = threadIdx.x;           // 0..511
  float se = 0.f, sl = 0.f;
#pragma unroll 4
  for (int j = 0; j < R1B; ++j) {
    float2 p = part2[(size_t)j * 512 + r];
    se += p.x; sl += p.y;
  }
  float lse = logf(se);                // no max-shift: se < 1e34
  float nll = lse - S_SCALE * finA[r];
  float sm  = lse - sl * (1.f / (float)NCLS);
  red[r] = 0.9f * nll + 0.1f * sm;
  __syncthreads();
  for (int s = 256; s > 0; s >>= 1) {
    if (r < s) red[r] += red[r + s];
    __syncthreads();
  }
  if (r == 0) out[0] = red[0] * (1.f / 512.f);
}

extern "C" void kernel_launch(void* const* d_in, const int* in_sizes, int n_in,
                              void* d_out, int out_size, void* d_ws, size_t ws_size,
                              hipStream_t stream) {
  (void)in_sizes; (void)n_in; (void)out_size;
  const float* emb = (const float*)d_in[0];
  const float* w   = (const float*)d_in[1];
  const int*   lab = (const int*)d_in[2];
  float* out = (float*)d_out;

  char* ws = (char*)d_ws;
  unsigned short* eb = (unsigned short*)ws;                       // 512 KB
  float* tlA   = (float*)(ws + 524288);
  float* ctmA  = tlA  + 512;
  float* finA  = ctmA + 512;
  float* tval  = finA + 512;
  float2* part  = (float2*)(ws + 524288 + 8192);                  // NB*512*8 = 6.4 MB
  float2* part2 = part + (size_t)NB * 512;                        // 64*512*8 = 256 KB
  const size_t wb_off = 7196672;                                  // end of part2, aligned
  unsigned short* wb = (unsigned short*)(ws + wb_off);            // NTILE*64KB = 102.5 MB
  float* sqpart = (float*)(ws + wb_off + (size_t)NTILE * 65536);  // 4*CPAD*4 = 1.6 MB
  const size_t need = wb_off + (size_t)NTILE * 65536 + (size_t)4 * CPAD * 4;
  // rnA/tpart aliased into the part region (consumed before k_gemm writes it)
  float*  rnA   = (float*)part;                                   // 2 KB
  float2* tpart = (float2*)((char*)part + 2048);                  // 64*512*8 = 256 KB

  if (ws_size >= need) {
    hipLaunchKernelGGL(k_w,     dim3(392), dim3(1024), 0, stream, w, wb, sqpart);
    hipLaunchKernelGGL(k0_norm, dim3(512), dim3(64),   0, stream, emb, eb, rnA);
    hipLaunchKernelGGL(k_tgt,   dim3(64),  dim3(512),  0, stream, emb, w, lab, tpart);
    hipLaunchKernelGGL(k_prep2, dim3(1),   dim3(512),  0, stream, tpart, rnA, ctmA, finA, tval);
    hipLaunchKernelGGL(k_gemm,  dim3(NB),  dim3(512),  0, stream,
                       wb, sqpart, eb, lab, ctmA, finA, tval, part);
  } else {
    hipLaunchKernelGGL(k0_norm_target_legacy, dim3(512), dim3(64), 0, stream, emb, w, lab, eb, tlA);
    hipLaunchKernelGGL(k_prep, dim3(1), dim3(512), 0, stream, tlA, ctmA, finA, tval);
    hipLaunchKernelGGL(k_gemm_legacy, dim3(NB), dim3(256), 0, stream,
                       w, eb, lab, ctmA, finA, tval, part);
  }
  hipLaunchKernelGGL(k_reduce1, dim3(R1B), dim3(512), 0, stream, part, part2);
  hipLaunchKernelGGL(k_loss,    dim3(1),   dim3(512), 0, stream, part2, finA, out);
}

// Round 7
// 418.115 us; speedup vs baseline: 1.1716x; 1.1221x over previous
//
#include <hip/hip_runtime.h>

#define KD    512
#define NCLS  100000
#define BC    64
#define NB    ((NCLS + BC - 1) / BC)   // 1563
#define NTILE 1564                     // padded tile count (covers c < 100096)
#define CPAD  100096                   // NTILE*64
#define R1B   64                       // stage-1 reduce blocks
#define R1C   25                       // strips per stage-1 block (64*25 >= 1563)
#define S_SCALE 64.0f
#define COS_M   0.87758256189037276f
#define SIN_M   0.47942553860420301f
#define THRESH (-0.87758256189037276f)
#define MM_C    0.23971276930210151f

typedef __attribute__((ext_vector_type(8))) short short8;
typedef __attribute__((ext_vector_type(4))) float f32x4;

union Pack8 { unsigned short u[8]; uint4 v; };

__device__ __forceinline__ unsigned short f2bf(float x) {
  unsigned int u = __float_as_uint(x);
  u += 0x7fffu + ((u >> 16) & 1u);   // round-to-nearest-even
  return (unsigned short)(u >> 16);
}

// ---- K0: row-normalize(e) -> ebF (bf16, MFMA A-fragment order) + rn --------
// ebF granule (rb, s, q, cl) holds row rb*16+cl, k = s*32+q*8 .. +8.
// ushort offset = rb*8192 + s*512 + q*128 + cl*8.
// Block r, lane l: holds k = l*8..+8 of row r -> s = l>>2, q = l&3.
__global__ void k0_norm(const float* __restrict__ emb,
                        unsigned short* __restrict__ ebF, float* __restrict__ rnA) {
  int r = blockIdx.x;
  int l = threadIdx.x;                 // 64 lanes, 8 elems each
  const float* src = emb + (size_t)r * KD + l * 8;
  float v[8];
  float ss = 0.f;
#pragma unroll
  for (int j = 0; j < 8; ++j) { v[j] = src[j]; ss += v[j] * v[j]; }
#pragma unroll
  for (int m = 1; m < 64; m <<= 1) ss += __shfl_xor(ss, m, 64);
  float rn = rsqrtf(ss);
  Pack8 p;
#pragma unroll
  for (int j = 0; j < 8; ++j) p.u[j] = f2bf(v[j] * rn);
  const size_t off = (size_t)(r >> 4) * 8192 + (l >> 2) * 512 + (l & 3) * 128 + (r & 15) * 8;
  *reinterpret_cast<uint4*>(ebF + off) = p.v;
  if (l == 0) rnA[r] = rn;
}

// ---- K_TGT: k-blocked target-column gather (DRAM row-burst locality) -------
__global__ __launch_bounds__(512)
void k_tgt(const float* __restrict__ emb, const float* __restrict__ w,
           const int* __restrict__ label, float2* __restrict__ tpart) {
  const int j = blockIdx.x;            // 0..63
  const int r = threadIdx.x;           // 0..511
  const int lab = label[r];
  const float* wc = w + lab;
  const float* er = emb + (size_t)r * KD + j * 8;
  float dot = 0.f, sq = 0.f;
#pragma unroll
  for (int kk = 0; kk < 8; ++kk) {
    float wv = wc[(size_t)(j * 8 + kk) * NCLS];
    float ev = er[kk];
    dot += ev * wv;
    sq  += wv * wv;
  }
  tpart[(size_t)j * 512 + r] = make_float2(dot, sq);
}

// ---- K_PREP2: reduce tpart -> tl; ctm/fin per row; t scalar ---------------
__global__ void k_prep2(const float2* __restrict__ tpart, const float* __restrict__ rnA,
                        float* __restrict__ ctmA, float* __restrict__ finA,
                        float* __restrict__ tval) {
  __shared__ float red[512];
  const int r = threadIdx.x;
  float dot = 0.f, sq = 0.f;
#pragma unroll 8
  for (int j = 0; j < 64; ++j) {
    float2 p = tpart[(size_t)j * 512 + r];
    dot += p.x; sq += p.y;
  }
  float tl = dot * rnA[r] * rsqrtf(sq);
  tl = fminf(1.f, fmaxf(-1.f, tl));
  red[r] = tl;
  __syncthreads();
  for (int s = 256; s > 0; s >>= 1) {
    if (r < s) red[r] += red[r + s];
    __syncthreads();
  }
  float st = sqrtf(fmaxf(0.f, 1.f - tl * tl));
  float ctm = tl * COS_M - st * SIN_M;
  ctmA[r] = ctm;
  finA[r] = (tl > THRESH) ? ctm : (tl - MM_C);
  if (r == 0) tval[0] = 0.01f * red[0] * (1.f / 512.f);
}

// ---- K_W: stream-pack w into wb (bf16 MFMA B-fragment order) + col sumsq ---
// Tile cb (64 cols x 512 k), granule (s, ct, q, cl): col ct*16+cl,
// k = s*32+q*8..+8.  ushort off = cb*32768 + s*2048 + ct*512 + q*128 + cl*8.
// Thread owns one column; k-octet o -> s = o>>2, q = o&3.
__global__ __launch_bounds__(1024)
void k_w(const float* __restrict__ w, unsigned short* __restrict__ wb,
         float* __restrict__ sqpart) {
  const int tid = threadIdx.x;
  const int ch  = blockIdx.x >> 2;
  const int kh  = blockIdx.x & 3;
  const int c   = ch * 1024 + tid;         // 0..100351
  const int cc  = (c < NCLS) ? c : (NCLS - 1);
  const bool valid = (c < NCLS);
  const bool wvalid = (c < CPAD);          // tiles exist only for c < 100096
  const int cb = c >> 6;
  const int ct = (c >> 4) & 3;
  const int cl = c & 15;
  unsigned short* gdst = wb + (size_t)cb * 32768 + ct * 512 + cl * 8;  // ushort units
  const float* srcc = w + cc;
  float sq = 0.f;
#pragma unroll 2
  for (int o16 = 0; o16 < 16; ++o16) {
    const int o = kh * 16 + o16;           // k-octet 0..63
    float v[8];
#pragma unroll
    for (int j = 0; j < 8; ++j)
      v[j] = __builtin_nontemporal_load(&srcc[(size_t)(o * 8 + j) * NCLS]);
    Pack8 p;
#pragma unroll
    for (int j = 0; j < 8; ++j) {
      float x = valid ? v[j] : 0.f;
      sq += x * x;
      p.u[j] = f2bf(x);
    }
    if (wvalid)
      *reinterpret_cast<uint4*>(gdst + (size_t)(o >> 2) * 2048 + (o & 3) * 128) = p.v;
  }
  if (wvalid) sqpart[(size_t)kh * CPAD + c] = sq;
}

// ---- K2: bf16 MFMA GEMM. B-tile reg-staged to LDS (linear 64 KB copy; tile
// already in fragment order -> conflict-free ds_write_b128/ds_read_b128),
// A loaded contiguously from fragment-ordered ebF (L2-resident).
// 8 waves x (64r x 64c). LDS ~68.5 KB -> 2 blocks/CU: block n+1 stages
// (HBM stream) while block n computes.
// NOTE: deliberately NO global_load_lds here — the two R5/R6 container
// failures are suspected GPU hangs from that primitive; plain reg-staging
// is the well-trodden path (costs only ~few % per guide m151).
__global__ __launch_bounds__(512, 4)
void k_gemm(const unsigned short* __restrict__ wb, const float* __restrict__ sqpart,
            const unsigned short* __restrict__ ebF,
            const int* __restrict__ label, const float* __restrict__ ctmA,
            const float* __restrict__ finA, const float* __restrict__ tval,
            float2* __restrict__ part) {
  __shared__ __align__(16) unsigned short Bs[BC * KD];   // 64 KB, fragment order
  __shared__ float invnS[BC];
  __shared__ float sE[512];
  __shared__ float sL[512];
  const int tid = threadIdx.x;
  const int wv = tid >> 6;             // wave 0..7
  const int l  = tid & 63;
  const int c0 = blockIdx.x * BC;

  // ---- bulk B stage: linear 64 KB copy, 16 B/thread/iter, fully coalesced --
  {
    const unsigned short* gsrc = wb + (size_t)blockIdx.x * 32768;
    uint4 st[8];
#pragma unroll
    for (int i = 0; i < 8; ++i)
      st[i] = *reinterpret_cast<const uint4*>(gsrc + (size_t)i * 4096 + tid * 8);
#pragma unroll
    for (int i = 0; i < 8; ++i)
      *reinterpret_cast<uint4*>(Bs + (size_t)i * 4096 + tid * 8) = st[i];
  }
  if (tid < BC) {
    const int c = c0 + tid;            // < 100096 <= CPAD
    float s = sqpart[0 * (size_t)CPAD + c] + sqpart[1 * (size_t)CPAD + c]
            + sqpart[2 * (size_t)CPAD + c] + sqpart[3 * (size_t)CPAD + c];
    invnS[tid] = (s > 0.f) ? rsqrtf(s) : 0.f;
  }
  __syncthreads();

  const int q  = l >> 4;
  const int cl = l & 15;
  const int rbase = wv * 64;
  const unsigned short* at = ebF + (size_t)(wv * 4) * 8192 + l * 8;  // rb = wv*4 (+rt)
  const unsigned short* btl = Bs + l * 8;
  f32x4 acc[4][4] = {};

#pragma unroll 1
  for (int s = 0; s < 16; ++s) {
    short8 a[4], b[4];
#pragma unroll
    for (int ct = 0; ct < 4; ++ct)
      b[ct] = *reinterpret_cast<const short8*>(btl + s * 2048 + ct * 512);
#pragma unroll
    for (int rt = 0; rt < 4; ++rt)
      a[rt] = *reinterpret_cast<const short8*>(at + (size_t)rt * 8192 + s * 512);
#pragma unroll
    for (int rt = 0; rt < 4; ++rt)
#pragma unroll
      for (int ct = 0; ct < 4; ++ct)
        acc[rt][ct] = __builtin_amdgcn_mfma_f32_16x16x32_bf16(a[rt], b[ct], acc[rt][ct], 0, 0, 0);
  }

  // ---- epilogue: colnorm + transform + per-row sums (all indices static) ---
  const float t = tval[0];
#pragma unroll
  for (int rt = 0; rt < 4; ++rt) {
#pragma unroll
    for (int rg = 0; rg < 4; ++rg) {
      const int row = rbase + rt * 16 + q * 4 + rg;
      const float ctm = ctmA[row];
      const float fin = finA[row];
      const int   lab = label[row];
      float se = 0.f, sl = 0.f;
#pragma unroll
      for (int ct = 0; ct < 4; ++ct) {
        const int cg = c0 + ct * 16 + cl;
        if (cg < NCLS) {
          float cosv = acc[rt][ct][rg] * invnS[ct * 16 + cl];
          cosv = fminf(1.f, fmaxf(-1.f, cosv));
          float logit = (cosv > ctm) ? cosv * (t + cosv) : cosv;
          if (cg == lab) logit = fin;
          float x = S_SCALE * logit;
          se += __expf(x);
          sl += x;
        }
      }
#pragma unroll
      for (int m = 1; m < 16; m <<= 1) {
        se += __shfl_xor(se, m, 64);
        sl += __shfl_xor(sl, m, 64);
      }
      if (cl == 0) { sE[row] = se; sL[row] = sl; }
    }
  }
  __syncthreads();

  part[(size_t)blockIdx.x * 512 + tid] = make_float2(sE[tid], sL[tid]);
}

// ================= legacy fallback path (R2 kernel set) =====================
__global__ void k0_norm_target_legacy(const float* __restrict__ emb, const float* __restrict__ w,
                               const int* __restrict__ label,
                               unsigned short* __restrict__ eb, float* __restrict__ tlA) {
  int r = blockIdx.x;
  int l = threadIdx.x;
  const float* src = emb + (size_t)r * KD + l * 8;
  float v[8];
  float ss = 0.f;
#pragma unroll
  for (int j = 0; j < 8; ++j) { v[j] = src[j]; ss += v[j] * v[j]; }
#pragma unroll
  for (int m = 1; m < 64; m <<= 1) ss += __shfl_xor(ss, m, 64);
  float rn = rsqrtf(ss);
  Pack8 p;
#pragma unroll
  for (int j = 0; j < 8; ++j) {
    float x = v[j] * rn;
    v[j] = x;
    p.u[j] = f2bf(x);
  }
  *reinterpret_cast<uint4*>(eb + (size_t)r * KD + l * 8) = p.v;
  int lab = label[r];
  float wv[8];
#pragma unroll
  for (int j = 0; j < 8; ++j) wv[j] = w[(size_t)(l * 8 + j) * NCLS + lab];
  float dot = 0.f, sq = 0.f;
#pragma unroll
  for (int j = 0; j < 8; ++j) { dot += v[j] * wv[j]; sq += wv[j] * wv[j]; }
#pragma unroll
  for (int m = 1; m < 64; m <<= 1) {
    dot += __shfl_xor(dot, m, 64);
    sq  += __shfl_xor(sq, m, 64);
  }
  if (l == 0) {
    float tl = dot * rsqrtf(sq);
    tlA[r] = fminf(1.f, fmaxf(-1.f, tl));
  }
}

__global__ void k_prep(const float* __restrict__ tlA, float* __restrict__ ctmA,
                       float* __restrict__ finA, float* __restrict__ tval) {
  __shared__ float red[512];
  int i = threadIdx.x;
  float tl = tlA[i];
  red[i] = tl;
  __syncthreads();
  for (int s = 256; s > 0; s >>= 1) {
    if (i < s) red[i] += red[i + s];
    __syncthreads();
  }
  float st = sqrtf(fmaxf(0.f, 1.f - tl * tl));
  float ctm = tl * COS_M - st * SIN_M;
  ctmA[i] = ctm;
  finA[i] = (tl > THRESH) ? ctm : (tl - MM_C);
  if (i == 0) tval[0] = 0.01f * red[0] * (1.f / 512.f);
}

__global__ __launch_bounds__(256, 2)
void k_gemm_legacy(const float* __restrict__ w, const unsigned short* __restrict__ eb,
            const int* __restrict__ label, const float* __restrict__ ctmA,
            const float* __restrict__ finA, const float* __restrict__ tval,
            float2* __restrict__ part) {
  __shared__ __align__(16) unsigned short Bs[BC * KD];
  __shared__ float ssW[4][BC];
  __shared__ float invnS[BC];
  __shared__ float sE[512];
  __shared__ float sL[512];
  const int tid = threadIdx.x;
  const int wv = tid >> 6;
  const int l  = tid & 63;
  const int c0 = blockIdx.x * BC;
  {
    const int c = l;
    const int cgc = (c0 + c < NCLS) ? (c0 + c) : (NCLS - 1);
    const float* wp = w + cgc;
    float ss = 0.f;
#pragma unroll 1
    for (int ph = 0; ph < 2; ++ph) {
      float vb[8][8];
#pragma unroll
      for (int b = 0; b < 8; ++b) {
        const int kb = wv * 8 + (ph * 8 + b) * 32;
#pragma unroll
        for (int j = 0; j < 8; ++j)
          vb[b][j] = __builtin_nontemporal_load(&wp[(size_t)(kb + j) * NCLS]);
      }
      __builtin_amdgcn_sched_barrier(0);
#pragma unroll
      for (int b = 0; b < 8; ++b) {
        const int kb = wv * 8 + (ph * 8 + b) * 32;
        Pack8 p;
#pragma unroll
        for (int j = 0; j < 8; ++j) {
          float x = vb[b][j];
          ss += x * x;
          p.u[j] = f2bf(x);
        }
        const int G = c * 64 + ((kb >> 3) ^ (c & 7));
        *reinterpret_cast<uint4*>(&Bs[G * 8]) = p.v;
      }
    }
    ssW[wv][c] = ss;
  }
  __syncthreads();
  if (tid < BC) {
    float s = ssW[0][tid] + ssW[1][tid] + ssW[2][tid] + ssW[3][tid];
    invnS[tid] = (s > 0.f) ? rsqrtf(s) : 0.f;
  }
  __syncthreads();
  const int q  = l >> 4;
  const int cl = l & 15;
  const int rbase = wv * 128;
  f32x4 acc[8][4] = {};
#pragma unroll 1
  for (int s = 0; s < 16; ++s) {
    const int k0 = s * 32 + q * 8;
    short8 a[8], b[4];
#pragma unroll
    for (int ct = 0; ct < 4; ++ct) {
      int c = ct * 16 + cl;
      int G = c * 64 + ((k0 >> 3) ^ (c & 7));
      b[ct] = *reinterpret_cast<const short8*>(&Bs[G * 8]);
    }
#pragma unroll
    for (int rt = 0; rt < 8; ++rt) {
      int row = rbase + rt * 16 + cl;
      a[rt] = *reinterpret_cast<const short8*>(eb + (size_t)row * KD + k0);
    }
#pragma unroll
    for (int rt = 0; rt < 8; ++rt)
#pragma unroll
      for (int ct = 0; ct < 4; ++ct)
        acc[rt][ct] = __builtin_amdgcn_mfma_f32_16x16x32_bf16(a[rt], b[ct], acc[rt][ct], 0, 0, 0);
  }
  const float t = tval[0];
#pragma unroll
  for (int rt = 0; rt < 8; ++rt) {
#pragma unroll
    for (int rg = 0; rg < 4; ++rg) {
      const int row = rbase + rt * 16 + q * 4 + rg;
      const float ctm = ctmA[row];
      const float fin = finA[row];
      const int   lab = label[row];
      float se = 0.f, sl = 0.f;
#pragma unroll
      for (int ct = 0; ct < 4; ++ct) {
        const int cg = c0 + ct * 16 + cl;
        if (cg < NCLS) {
          float cosv = acc[rt][ct][rg] * invnS[ct * 16 + cl];
          cosv = fminf(1.f, fmaxf(-1.f, cosv));
          float logit = (cosv > ctm) ? cosv * (t + cosv) : cosv;
          if (cg == lab) logit = fin;
          float x = S_SCALE * logit;
          se += __expf(x);
          sl += x;
        }
      }
#pragma unroll
      for (int m = 1; m < 16; m <<= 1) {
        se += __shfl_xor(se, m, 64);
        sl += __shfl_xor(sl, m, 64);
      }
      if (cl == 0) { sE[row] = se; sL[row] = sl; }
    }
  }
  __syncthreads();
  {
    float2* dst = part + (size_t)blockIdx.x * 512;
    dst[tid]       = make_float2(sE[tid],       sL[tid]);
    dst[tid + 256] = make_float2(sE[tid + 256], sL[tid + 256]);
  }
}

// ---- K3a: stage-1 reduce over strips (coalesced) ---------------------------
__global__ void k_reduce1(const float2* __restrict__ part, float2* __restrict__ part2) {
  const int j = blockIdx.x;            // 0..63
  const int r = threadIdx.x;           // 0..511
  const int i0 = j * R1C;
  const int i1 = (i0 + R1C < NB) ? (i0 + R1C) : NB;
  float se = 0.f, sl = 0.f;
  for (int i = i0; i < i1; ++i) {
    float2 p = part[(size_t)i * 512 + r];
    se += p.x; sl += p.y;
  }
  part2[(size_t)j * 512 + r] = make_float2(se, sl);
}

// ---- K3b: stage-2 reduce + final loss (single block) -----------------------
__global__ void k_loss(const float2* __restrict__ part2, const float* __restrict__ finA,
                       float* __restrict__ out) {
  __shared__ float red[512];
  const int r = threadIdx.x;           // 0..511
  float se = 0.f, sl = 0.f;
#pragma unroll 4
  for (int j = 0; j < R1B; ++j) {
    float2 p = part2[(size_t)j * 512 + r];
    se += p.x; sl += p.y;
  }
  float lse = logf(se);                // no max-shift: se < 1e34
  float nll = lse - S_SCALE * finA[r];
  float sm  = lse - sl * (1.f / (float)NCLS);
  red[r] = 0.9f * nll + 0.1f * sm;
  __syncthreads();
  for (int s = 256; s > 0; s >>= 1) {
    if (r < s) red[r] += red[r + s];
    __syncthreads();
  }
  if (r == 0) out[0] = red[0] * (1.f / 512.f);
}

extern "C" void kernel_launch(void* const* d_in, const int* in_sizes, int n_in,
                              void* d_out, int out_size, void* d_ws, size_t ws_size,
                              hipStream_t stream) {
  (void)in_sizes; (void)n_in; (void)out_size;
  const float* emb = (const float*)d_in[0];
  const float* w   = (const float*)d_in[1];
  const int*   lab = (const int*)d_in[2];
  float* out = (float*)d_out;

  char* ws = (char*)d_ws;
  unsigned short* eb = (unsigned short*)ws;                       // 512 KB (ebF / legacy eb)
  float* tlA   = (float*)(ws + 524288);
  float* ctmA  = tlA  + 512;
  float* finA  = ctmA + 512;
  float* tval  = finA + 512;
  float2* part  = (float2*)(ws + 524288 + 8192);                  // NB*512*8 = 6.4 MB
  float2* part2 = part + (size_t)NB * 512;                        // 64*512*8 = 256 KB
  const size_t wb_off = 7196672;                                  // end of part2, aligned
  unsigned short* wb = (unsigned short*)(ws + wb_off);            // NTILE*64KB = 102.5 MB
  float* sqpart = (float*)(ws + wb_off + (size_t)NTILE * 65536);  // 4*CPAD*4 = 1.6 MB
  const size_t need = wb_off + (size_t)NTILE * 65536 + (size_t)4 * CPAD * 4;
  // rnA/tpart aliased into the part region (consumed before k_gemm writes it)
  float*  rnA   = (float*)part;                                   // 2 KB
  float2* tpart = (float2*)((char*)part + 2048);                  // 64*512*8 = 256 KB

  if (ws_size >= need) {
    hipLaunchKernelGGL(k_w,     dim3(392), dim3(1024), 0, stream, w, wb, sqpart);
    hipLaunchKernelGGL(k0_norm, dim3(512), dim3(64),   0, stream, emb, eb, rnA);
    hipLaunchKernelGGL(k_tgt,   dim3(64),  dim3(512),  0, stream, emb, w, lab, tpart);
    hipLaunchKernelGGL(k_prep2, dim3(1),   dim3(512),  0, stream, tpart, rnA, ctmA, finA, tval);
    hipLaunchKernelGGL(k_gemm,  dim3(NB),  dim3(512),  0, stream,
                       wb, sqpart, eb, lab, ctmA, finA, tval, part);
  } else {
    hipLaunchKernelGGL(k0_norm_target_legacy, dim3(512), dim3(64), 0, stream, emb, w, lab, eb, tlA);
    hipLaunchKernelGGL(k_prep, dim3(1), dim3(512), 0, stream, tlA, ctmA, finA, tval);
    hipLaunchKernelGGL(k_gemm_legacy, dim3(NB), dim3(256), 0, stream,
                       w, eb, lab, ctmA, finA, tval, part);
  }
  hipLaunchKernelGGL(k_reduce1, dim3(R1B), dim3(512), 0, stream, part, part2);
  hipLaunchKernelGGL(k_loss,    dim3(1),   dim3(512), 0, stream, part2, finA, out);
}